// Round 6
// baseline (243.221 us; speedup 1.0000x reference)
//
#include <hip/hip_runtime.h>
#include <hip/hip_bf16.h>
#include <stdint.h>

#define B_   4
#define CIN  32
#define COUT 32
#define NV   163842
#define K7   7

typedef short bf16x8 __attribute__((ext_vector_type(8)));
typedef float f32x4  __attribute__((ext_vector_type(4)));
typedef float f32x4u __attribute__((ext_vector_type(4), aligned(4)));  // 4-B-aligned vec store

__device__ inline uint16_t f2bf(float f) {
    uint32_t u = __float_as_uint(f);
    uint32_t r = (u + 0x7FFFu + ((u >> 16) & 1u)) >> 16;
    return (uint16_t)r;
}

// --- Kernel A: W (32 x 224) f32 -> bf16 ---------------------------------
__global__ void k_convw(const float* __restrict__ W, uint16_t* __restrict__ Wb) {
    int i = blockIdx.x * 256 + threadIdx.x;
    if (i < COUT * K7 * CIN) Wb[i] = f2bf(W[i]);
}

// --- Kernel B: x (B, 32, N) f32 -> xt (N, B, 32) bf16, LDS-staged --------
// x reads are streamed (non-temporal: zero reuse); xt writes stay cached
// (they are the gather working set).
__global__ __launch_bounds__(256) void k_transpose(const float* __restrict__ x,
                                                   uint16_t* __restrict__ xt) {
    __shared__ uint16_t lds[128 * 132];         // 128 rows x 264B (256 + 8 pad)
    const int v0 = blockIdx.x * 128;
    const int t  = threadIdx.x;
    const int vl = t & 127;                     // vertex lane
    const int h  = t >> 7;                      // channel half (0..1)
    const int v  = v0 + vl;
    const int vc = (v < NV) ? v : (NV - 1);

    #pragma unroll
    for (int b = 0; b < B_; ++b) {
        const float* xb = x + (size_t)b * CIN * NV + (size_t)h * 16 * NV + vc;
        #pragma unroll
        for (int q = 0; q < 2; ++q) {
            bf16x8 pk;
            #pragma unroll
            for (int i = 0; i < 8; ++i)
                ((uint16_t*)&pk)[i] = f2bf(__builtin_nontemporal_load(&xb[(size_t)(q * 8 + i) * NV]));
            *(bf16x8*)&lds[vl * 132 + b * 32 + h * 16 + q * 8] = pk;
        }
    }
    __syncthreads();

    const size_t lim = ((size_t)(NV - v0)) * 256;   // valid bytes in this tile
    uint16_t* dst = xt + (size_t)v0 * 128;
    #pragma unroll
    for (int s = 0; s < 8; ++s) {
        const int f = s * 4096 + t * 16;            // byte offset in 32KB tile
        if ((size_t)f < lim) {
            const int row = f >> 8;
            const int w   = f & 255;
            bf16x8 d = *(bf16x8*)&lds[row * 132 + (w >> 1)];
            *(bf16x8*)(dst + (f >> 1)) = d;
        }
    }
}

// --- Kernel C: gather + MFMA, swapped operands, nt output stores ---------
// A = gathered X (row = lane&15 = vertex), B = W (col = lane&15 = o).
// out stores are non-temporal so the 94-MB write stream does not evict
// the xt gather working set from L2.
#define MFMA_BF16 __builtin_amdgcn_mfma_f32_16x16x32_bf16

__global__ __launch_bounds__(256) void k_main(const uint16_t* __restrict__ xt,
                                              const uint16_t* __restrict__ Wb,
                                              const float* __restrict__ bias,
                                              const int* __restrict__ neigh,
                                              float* __restrict__ out) {
    const int tid  = threadIdx.x;
    const int lane = tid & 63;
    const int wv   = tid >> 6;
    const int vb   = blockIdx.x * 64 + wv * 16;
    const int l15  = lane & 15;
    const int g    = lane >> 4;                 // k-group 0..3
    const int v    = vb + l15;
    const int vv   = (v < NV) ? v : (NV - 1);

    // Neighbor indices (read once -> non-temporal)
    int nidx[K7];
    #pragma unroll
    for (int j = 0; j < K7; ++j) nidx[j] = __builtin_nontemporal_load(&neigh[(size_t)vv * K7 + j]);

    // Gathers: xf[j][b] = 16B of row nidx[j], batch b, k-group g  (A-frags)
    bf16x8 xf[K7][B_];
    #pragma unroll
    for (int j = 0; j < K7; ++j) {
        const uint16_t* row = xt + (size_t)nidx[j] * 128;
        #pragma unroll
        for (int b = 0; b < B_; ++b)
            xf[j][b] = *(const bf16x8*)(row + b * 32 + g * 8);
    }

    // W fragments (B-frags): col = l15 = o, 8 contiguous k at g*8 (hot, cached)
    bf16x8 wf[2][K7];
    #pragma unroll
    for (int t = 0; t < 2; ++t)
        #pragma unroll
        for (int j = 0; j < K7; ++j)
            wf[t][j] = *(const bf16x8*)(Wb + (size_t)(t * 16 + l15) * (K7 * CIN) + j * CIN + g * 8);

    f32x4 acc[B_][2];
    #pragma unroll
    for (int b = 0; b < B_; ++b) {
        acc[b][0] = (f32x4){0.f, 0.f, 0.f, 0.f};
        acc[b][1] = (f32x4){0.f, 0.f, 0.f, 0.f};
    }

    #pragma unroll
    for (int j = 0; j < K7; ++j)
        #pragma unroll
        for (int b = 0; b < B_; ++b) {
            acc[b][0] = MFMA_BF16(xf[j][b], wf[0][j], acc[b][0], 0, 0, 0);
            acc[b][1] = MFMA_BF16(xf[j][b], wf[1][j], acc[b][1], 0, 0, 0);
        }

    // Epilogue: D[v][o] -> lane stores 4 consecutive v at channel o = l15
    const float bia0 = bias[l15];
    const float bia1 = bias[l15 + 16];
    const int vrow = vb + g * 4;

    if (vb + 15 < NV) {
        #pragma unroll
        for (int b = 0; b < B_; ++b) {
            float* ob = out + (size_t)b * COUT * NV + vrow;
            f32x4 s0, s1;
            #pragma unroll
            for (int r = 0; r < 4; ++r) { s0[r] = acc[b][0][r] + bia0; s1[r] = acc[b][1][r] + bia1; }
            __builtin_nontemporal_store((f32x4u)s0, (f32x4u*)(ob + (size_t)l15 * NV));
            __builtin_nontemporal_store((f32x4u)s1, (f32x4u*)(ob + (size_t)(16 + l15) * NV));
        }
    } else {
        #pragma unroll
        for (int b = 0; b < B_; ++b)
            #pragma unroll
            for (int r = 0; r < 4; ++r) {
                int vr = vrow + r;
                if (vr < NV) {
                    __builtin_nontemporal_store(acc[b][0][r] + bia0,
                        &out[(size_t)b * COUT * NV + (size_t)l15 * NV + vr]);
                    __builtin_nontemporal_store(acc[b][1][r] + bia1,
                        &out[(size_t)b * COUT * NV + (size_t)(16 + l15) * NV + vr]);
                }
            }
    }
}

extern "C" void kernel_launch(void* const* d_in, const int* in_sizes, int n_in,
                              void* d_out, int out_size, void* d_ws, size_t ws_size,
                              hipStream_t stream) {
    const float* x     = (const float*)d_in[0];
    const float* W     = (const float*)d_in[1];
    const float* bias  = (const float*)d_in[2];
    const int*   neigh = (const int*)d_in[3];
    float* out = (float*)d_out;

    uint16_t* xt = (uint16_t*)d_ws;                       // NV*B*32 bf16 = 41.9 MB
    uint16_t* Wb = xt + (size_t)NV * B_ * CIN;            // 7168 bf16

    k_convw<<<(COUT * K7 * CIN + 255) / 256, 256, 0, stream>>>(W, Wb);

    dim3 g1((NV + 127) / 128, 1);
    k_transpose<<<g1, 256, 0, stream>>>(x, xt);

    dim3 g2((NV + 63) / 64, 1);
    k_main<<<g2, 256, 0, stream>>>(xt, Wb, bias, neigh, out);
}

// Round 7
// 229.454 us; speedup vs baseline: 1.0600x; 1.0600x over previous
//
#include <hip/hip_runtime.h>
#include <hip/hip_bf16.h>
#include <stdint.h>

#define B_   4
#define CIN  32
#define COUT 32
#define NV   163842
#define K7   7

typedef short bf16x8 __attribute__((ext_vector_type(8)));
typedef float f32x4  __attribute__((ext_vector_type(4)));
typedef float f32x4u __attribute__((ext_vector_type(4), aligned(4)));  // 4-B-aligned vec store

__device__ inline uint16_t f2bf(float f) {
    uint32_t u = __float_as_uint(f);
    uint32_t r = (u + 0x7FFFu + ((u >> 16) & 1u)) >> 16;
    return (uint16_t)r;
}

// --- Kernel B: x (B, 32, N) f32 -> xt (N, B, 32) bf16, LDS-staged --------
// Block 0 additionally converts W (32 x 224) f32 -> bf16 (fused k_convw).
// x reads are non-temporal (zero reuse); xt writes stay cached.
__global__ __launch_bounds__(256) void k_transpose(const float* __restrict__ x,
                                                   uint16_t* __restrict__ xt,
                                                   const float* __restrict__ W,
                                                   uint16_t* __restrict__ Wb) {
    __shared__ uint16_t lds[128 * 132];         // 128 rows x 264B (256 + 8 pad)
    const int v0 = blockIdx.x * 128;
    const int t  = threadIdx.x;

    if (blockIdx.x == 0) {                      // fused W conversion: 7168 elems
        #pragma unroll
        for (int s = 0; s < 28; ++s) {
            int i = s * 256 + t;
            Wb[i] = f2bf(W[i]);
        }
    }

    const int vl = t & 127;                     // vertex lane
    const int h  = t >> 7;                      // channel half (0..1)
    const int v  = v0 + vl;
    const int vc = (v < NV) ? v : (NV - 1);

    #pragma unroll
    for (int b = 0; b < B_; ++b) {
        const float* xb = x + (size_t)b * CIN * NV + (size_t)h * 16 * NV + vc;
        #pragma unroll
        for (int q = 0; q < 2; ++q) {
            bf16x8 pk;
            #pragma unroll
            for (int i = 0; i < 8; ++i)
                ((uint16_t*)&pk)[i] = f2bf(__builtin_nontemporal_load(&xb[(size_t)(q * 8 + i) * NV]));
            *(bf16x8*)&lds[vl * 132 + b * 32 + h * 16 + q * 8] = pk;
        }
    }
    __syncthreads();

    const size_t lim = ((size_t)(NV - v0)) * 256;   // valid bytes in this tile
    uint16_t* dst = xt + (size_t)v0 * 128;
    #pragma unroll
    for (int s = 0; s < 8; ++s) {
        const int f = s * 4096 + t * 16;            // byte offset in 32KB tile
        if ((size_t)f < lim) {
            const int row = f >> 8;
            const int w   = f & 255;
            bf16x8 d = *(bf16x8*)&lds[row * 132 + (w >> 1)];
            *(bf16x8*)(dst + (f >> 1)) = d;
        }
    }
}

// --- Kernel C: gather + MFMA, swapped operands (r5 epilogue: cached stores)
// A = gathered X (row = lane&15 = vertex), B = W (col = lane&15 = o).
// D[v][o]: each lane holds 4 consecutive vertices at one channel ->
// vectorized dwordx4 stores; L2 write-combines adjacent waves' 64-B halves.
#define MFMA_BF16 __builtin_amdgcn_mfma_f32_16x16x32_bf16

__global__ __launch_bounds__(256) void k_main(const uint16_t* __restrict__ xt,
                                              const uint16_t* __restrict__ Wb,
                                              const float* __restrict__ bias,
                                              const int* __restrict__ neigh,
                                              float* __restrict__ out) {
    const int tid  = threadIdx.x;
    const int lane = tid & 63;
    const int wv   = tid >> 6;
    const int vb   = blockIdx.x * 64 + wv * 16;
    const int l15  = lane & 15;
    const int g    = lane >> 4;                 // k-group 0..3
    const int v    = vb + l15;
    const int vv   = (v < NV) ? v : (NV - 1);

    // Neighbor indices (read once -> non-temporal)
    int nidx[K7];
    #pragma unroll
    for (int j = 0; j < K7; ++j) nidx[j] = __builtin_nontemporal_load(&neigh[(size_t)vv * K7 + j]);

    // Gathers: xf[j][b] = 16B of row nidx[j], batch b, k-group g  (A-frags)
    bf16x8 xf[K7][B_];
    #pragma unroll
    for (int j = 0; j < K7; ++j) {
        const uint16_t* row = xt + (size_t)nidx[j] * 128;
        #pragma unroll
        for (int b = 0; b < B_; ++b)
            xf[j][b] = *(const bf16x8*)(row + b * 32 + g * 8);
    }

    // W fragments (B-frags): col = l15 = o, 8 contiguous k at g*8 (hot, cached)
    bf16x8 wf[2][K7];
    #pragma unroll
    for (int t = 0; t < 2; ++t)
        #pragma unroll
        for (int j = 0; j < K7; ++j)
            wf[t][j] = *(const bf16x8*)(Wb + (size_t)(t * 16 + l15) * (K7 * CIN) + j * CIN + g * 8);

    f32x4 acc[B_][2];
    #pragma unroll
    for (int b = 0; b < B_; ++b) {
        acc[b][0] = (f32x4){0.f, 0.f, 0.f, 0.f};
        acc[b][1] = (f32x4){0.f, 0.f, 0.f, 0.f};
    }

    #pragma unroll
    for (int j = 0; j < K7; ++j)
        #pragma unroll
        for (int b = 0; b < B_; ++b) {
            acc[b][0] = MFMA_BF16(xf[j][b], wf[0][j], acc[b][0], 0, 0, 0);
            acc[b][1] = MFMA_BF16(xf[j][b], wf[1][j], acc[b][1], 0, 0, 0);
        }

    // Epilogue: D[v][o] -> lane stores 4 consecutive v at channel o = l15
    const float bia0 = bias[l15];
    const float bia1 = bias[l15 + 16];
    const int vrow = vb + g * 4;

    if (vb + 15 < NV) {
        #pragma unroll
        for (int b = 0; b < B_; ++b) {
            float* ob = out + (size_t)b * COUT * NV + vrow;
            f32x4 s0, s1;
            #pragma unroll
            for (int r = 0; r < 4; ++r) { s0[r] = acc[b][0][r] + bia0; s1[r] = acc[b][1][r] + bia1; }
            *(f32x4u*)(ob + (size_t)l15 * NV)        = s0;
            *(f32x4u*)(ob + (size_t)(16 + l15) * NV) = s1;
        }
    } else {
        #pragma unroll
        for (int b = 0; b < B_; ++b)
            #pragma unroll
            for (int r = 0; r < 4; ++r) {
                int vr = vrow + r;
                if (vr < NV) {
                    out[(size_t)b * COUT * NV + (size_t)l15 * NV + vr]        = acc[b][0][r] + bia0;
                    out[(size_t)b * COUT * NV + (size_t)(16 + l15) * NV + vr] = acc[b][1][r] + bia1;
                }
            }
    }
}

extern "C" void kernel_launch(void* const* d_in, const int* in_sizes, int n_in,
                              void* d_out, int out_size, void* d_ws, size_t ws_size,
                              hipStream_t stream) {
    const float* x     = (const float*)d_in[0];
    const float* W     = (const float*)d_in[1];
    const float* bias  = (const float*)d_in[2];
    const int*   neigh = (const int*)d_in[3];
    float* out = (float*)d_out;

    uint16_t* xt = (uint16_t*)d_ws;                       // NV*B*32 bf16 = 41.9 MB
    uint16_t* Wb = xt + (size_t)NV * B_ * CIN;            // 7168 bf16

    dim3 g1((NV + 127) / 128, 1);
    k_transpose<<<g1, 256, 0, stream>>>(x, xt, W, Wb);

    dim3 g2((NV + 63) / 64, 1);
    k_main<<<g2, 256, 0, stream>>>(xt, Wb, bias, neigh, out);
}